// Round 13
// baseline (5063.474 us; speedup 1.0000x reference)
//
#include <hip/hip_runtime.h>
#include <hip/hip_bf16.h>
#include <math.h>

#define SEQL   4096
#define NITEMS 512
#define HID    256
#define NLAY   16
#define QS     64      // ring slots = 8 chunks x 8 steps
#define CHUNK  8
#define NCHUNK (SEQL / CHUNK)
#define TPB    4

typedef float f4 __attribute__((ext_vector_type(4)));

// Workspace layout (float offsets)
#define P_OFF   ((size_t)0)                               // P[4][SEQL][HID]
#define H_OFF   (P_OFF + (size_t)4*SEQL*HID)              // Hring[4][NLAY][QS][HID]
#define AP_OFF  (H_OFF + (size_t)4*NLAY*QS*HID)           // Apart[4][NLAY][QS][HID]
#define HF_OFF  (AP_OFF + (size_t)4*NLAY*QS*HID)          // hfinal[4][HID]
#define FLAG_OFF_FLOATS (HF_OFF + (size_t)1024)
#define NFLAGS 256

// ---------------------------------------------------------------------------
__device__ __forceinline__ float ld_coh_b32(const float* p) {
    float r;
    asm volatile("global_load_dword %0, %1, off sc0 sc1" : "=v"(r) : "v"(p));
    return r;
}
__device__ __forceinline__ void st_coh_b32(float* p, float v) {
    asm volatile("global_store_dword %0, %1, off sc0 sc1" :: "v"(p), "v"(v) : "memory");
}
__device__ __forceinline__ void st_coh_u32(unsigned* p, unsigned v) {
    asm volatile("global_store_dword %0, %1, off sc0 sc1" :: "v"(p), "v"(v) : "memory");
}
__device__ __forceinline__ unsigned uload(const unsigned* p) {
    return __hip_atomic_load(p, __ATOMIC_RELAXED, __HIP_MEMORY_SCOPE_AGENT);
}

#define SBAR()  { __builtin_amdgcn_s_barrier(); __builtin_amdgcn_sched_barrier(0); }
#define LGKM0() { asm volatile("s_waitcnt lgkmcnt(0)" ::: "memory"); __builtin_amdgcn_sched_barrier(0); }
#define VMW0()  { asm volatile("s_waitcnt vmcnt(0)" ::: "memory"); __builtin_amdgcn_sched_barrier(0); }
// Wait own-wave vmem AND pin reg as output so uses can't hoist above (rule 18).
#define WAIT_PIN(reg) { asm volatile("s_waitcnt vmcnt(0)" : "+v"(reg) :: "memory"); \
                        __builtin_amdgcn_sched_barrier(0); }

__device__ __forceinline__ void spin_ge(const unsigned* p, unsigned target, bool* dead) {
    if (*dead) return;
    unsigned it = 0;
    while (uload(p) < target) {
        __builtin_amdgcn_s_sleep(1);
        if (++it > (1u << 20)) { *dead = true; break; }
    }
}

__device__ __forceinline__ float tanh_fast(float x) {
    return 1.f - __fdividef(2.f, __expf(2.f * x) + 1.f);
}

// --- quad_perm broadcast core ---------------------------------------------
// Hq[idx=4b+a][lane] = h[chunkbase + 16b + 4a + (lane&3)], built by
// ds_bpermute from the wave's h register (lane L holds h[chunkbase+L]):
// addr = 4*(lane&3), offset immediate = 16*idx (bytes) = lane offset 16b+4a.
// FMA for k-offset i=16b+4a+d: quad_perm:[d,d,d,d] on Hq[4b+a] gives every
// lane h[chunkbase+i] (lane 4n+j reads lane 4n+d, whose (lane&3)=d).
// Weights are PLAIN: w[i] = W[j][chunkbase+i]. No pre-permutation.
#define BP1(DST, SRC, OFF) \
    asm volatile("ds_bpermute_b32 %0, %1, %2 offset:" #OFF \
                 : "=v"(DST) : "v"(abase), "v"(SRC));
#define BPERM16(SRC) \
    BP1(Hq0,SRC,0)    BP1(Hq1,SRC,16)   BP1(Hq2,SRC,32)   BP1(Hq3,SRC,48)   \
    BP1(Hq4,SRC,64)   BP1(Hq5,SRC,80)   BP1(Hq6,SRC,96)   BP1(Hq7,SRC,112)  \
    BP1(Hq8,SRC,128)  BP1(Hq9,SRC,144)  BP1(Hq10,SRC,160) BP1(Hq11,SRC,176) \
    BP1(Hq12,SRC,192) BP1(Hq13,SRC,208) BP1(Hq14,SRC,224) BP1(Hq15,SRC,240)

#define FMAC_QP(ACC, HREG, W, D) \
    asm volatile("v_fmac_f32_dpp %0, %1, %2 quad_perm:[" #D "," #D "," #D "," #D "] row_mask:0xf bank_mask:0xf" \
                 : "+v"(ACC) : "v"(HREG), "v"(W));
#define FMAC_QUAD(HREG, WB) \
    FMAC_QP(acc0, HREG, w[WB+0], 0) FMAC_QP(acc1, HREG, w[WB+1], 1) \
    FMAC_QP(acc2, HREG, w[WB+2], 2) FMAC_QP(acc3, HREG, w[WB+3], 3)

#define FMAC_ALL() \
    FMAC_QUAD(Hq0, 0)   FMAC_QUAD(Hq1, 4)   FMAC_QUAD(Hq2, 8)   FMAC_QUAD(Hq3, 12)  \
    FMAC_QUAD(Hq4, 16)  FMAC_QUAD(Hq5, 20)  FMAC_QUAD(Hq6, 24)  FMAC_QUAD(Hq7, 28)  \
    FMAC_QUAD(Hq8, 32)  FMAC_QUAD(Hq9, 36)  FMAC_QUAD(Hq10, 40) FMAC_QUAD(Hq11, 44) \
    FMAC_QUAD(Hq12, 48) FMAC_QUAD(Hq13, 52) FMAC_QUAD(Hq14, 56) FMAC_QUAD(Hq15, 60)

// ---------------------------------------------------------------------------
// Kernel 1: input projection P[c][t][j] = sum_k Wih0_c[j,k] * x[t,k,c]
__global__ __launch_bounds__(1024) void proj_kernel(
    const float* __restrict__ x, const float* __restrict__ Wlp,
    const float* __restrict__ Wlpv, float* __restrict__ P)
{
    __shared__ float xs[TPB][4][NITEMS];
    const int tid = threadIdx.x;
    const int t0 = blockIdx.x * TPB;

    #pragma unroll
    for (int tt = 0; tt < TPB; ++tt) {
        const float2* src = (const float2*)(x + (size_t)(t0 + tt) * NITEMS * 4);
        float2 v = src[tid];
        int e = 2 * tid;
        xs[tt][e & 3][e >> 2]       = v.x;
        xs[tt][(e + 1) & 3][e >> 2] = v.y;
    }
    __syncthreads();

    const int c = tid >> 8, j = tid & 255;
    const float* W = (c == 1) ? Wlpv : Wlp;
    const float4* row = (const float4*)(W + (size_t)j * NITEMS);
    float acc[TPB] = {0.f, 0.f, 0.f, 0.f};
    #pragma unroll 4
    for (int k4 = 0; k4 < NITEMS / 4; ++k4) {
        float4 w = row[k4];
        #pragma unroll
        for (int tt = 0; tt < TPB; ++tt) {
            float4 xv = *(const float4*)(&xs[tt][c][k4 * 4]);
            acc[tt] = fmaf(w.x, xv.x, fmaf(w.y, xv.y, fmaf(w.z, xv.z, fmaf(w.w, xv.w, acc[tt]))));
        }
    }
    #pragma unroll
    for (int tt = 0; tt < TPB; ++tt)
        P[((size_t)c * SEQL + (t0 + tt)) * HID + j] = acc[tt];
}

// ---------------------------------------------------------------------------
// Kernel 2: layer-pipelined RNN. Chunked handshakes + early-poll + next-chunk
// prefetch (R12); quad_perm DPP matvec (this round's A/B vs row_ror).
__global__ __launch_bounds__(1024) void rnn_pipe(
    const float* __restrict__ lp_Wih,  const float* __restrict__ lp_Whh,
    const float* __restrict__ lp_bih,  const float* __restrict__ lp_bhh,
    const float* __restrict__ lpv_Wih, const float* __restrict__ lpv_Whh,
    const float* __restrict__ lpv_bih, const float* __restrict__ lpv_bhh,
    const float* __restrict__ P, float* __restrict__ Hring,
    float* __restrict__ Apart, float* __restrict__ hfinal,
    unsigned* __restrict__ Hflag, unsigned* __restrict__ Aflag)
{
    __shared__ __align__(16) float part2[2][1024];
    __shared__ int pf_lds[2];   // [0]=next-chunk data ready, [1]=next-chunk bp ok

    const int b = blockIdx.x;
    if (b >= 124) return;
    const int tid = threadIdx.x;

    const int c = b / 31;
    const int r = b % 31;
    const int role = (r < NLAY) ? 0 : 1;
    const int l = (r < NLAY) ? r : (r - NLAY + 1);

    const float* Wih = (c == 1) ? lpv_Wih : lp_Wih;
    const float* Whh = (c == 1) ? lpv_Whh : lp_Whh;
    const float* bih = (c == 1) ? lpv_bih : lp_bih;
    const float* bhh = (c == 1) ? lpv_bhh : lp_bhh;

    const int j    = tid & 255;
    const int c4   = tid >> 8;
    const int lane = tid & 63;
    const int m    = (c4 << 6) | lane;
    const bool first = ((tid & 192) == 0);
    bool dead = false;

    const int abase = 4 * (lane & 3);   // bpermute base addr (offset imm adds 16*idx)
    float Hq0, Hq1, Hq2, Hq3, Hq4, Hq5, Hq6, Hq7;
    float Hq8, Hq9, Hq10, Hq11, Hq12, Hq13, Hq14, Hq15;

    if (role == 0) {
        // ===================== B role =====================
        const bool l0 = (l == 0);

        float w[64];
        {
            const f4* wrow = (const f4*)(Whh + ((size_t)l * HID + j) * HID + (c4 << 6));
            #pragma unroll
            for (int i = 0; i < 16; ++i) {
                f4 v = wrow[i];
                w[4*i+0] = v.x; w[4*i+1] = v.y; w[4*i+2] = v.z; w[4*i+3] = v.w;
            }
        }
        #pragma unroll
        for (int i = 0; i < 64; ++i) asm volatile("" : "+v"(w[i]));

        const float bias_m = bih[l * HID + m] + bhh[l * HID + m];

        const float*    Psrc  = P + (size_t)c * SEQL * HID;
        const float*    apbuf = Apart + ((size_t)(c * NLAY + l) * QS) * HID;
        const unsigned* af    = Aflag + c * NLAY + l;
        unsigned*       myHfl = Hflag + c * NLAY + l;
        const unsigned* consA = Aflag + c * NLAY + l + 1;   // valid when l<15
        float*          Hout  = Hring + ((size_t)(c * NLAY + l) * QS) * HID;
        float*          hfin  = hfinal + (size_t)c * HID;

        float h = 0.f;
        float ap8[CHUNK], apn[CHUNK];
        bool havePF = false;

        for (int k = 0; k < NCHUNK; ++k) {
            // ---------- chunk top ----------
            int pf2ok = 1;
            if (k >= CHUNK && l < NLAY - 1) pf2ok = pf_lds[1];
            const bool needbar = (!havePF && !l0) || !pf2ok;
            if (needbar) {
                if (tid == 0) {
                    if (!havePF && !l0) spin_ge(af, (unsigned)(k + 1), &dead);
                    if (!pf2ok) spin_ge(consA, (unsigned)(k - 7), &dead);
                }
                SBAR();
            }
            if (havePF) {
                VMW0();
                #pragma unroll
                for (int s = 0; s < CHUNK; ++s) ap8[s] = apn[s];
            } else {
                if (l0) {
                    #pragma unroll
                    for (int s = 0; s < CHUNK; ++s)
                        ap8[s] = Psrc[(size_t)(CHUNK * k + s) * HID + m];
                } else {
                    const int sbase = (k & 7) * CHUNK;
                    #pragma unroll
                    for (int s = 0; s < CHUNK; ++s)
                        ap8[s] = ld_coh_b32(apbuf + (size_t)(sbase + s) * HID + m);
                    VMW0();
                }
            }
            // issue next-chunk polls (non-blocking; checked at s==1)
            unsigned afv = 0u, bpv = 0u;
            const bool pollIn = (!l0) && (k + 1 < NCHUNK);
            const bool pollBp = (l < NLAY - 1) && (k + 1 >= CHUNK) && (k + 1 < NCHUNK);
            if (tid == 64 && pollIn)
                asm volatile("global_load_dword %0, %1, off sc0 sc1" : "=v"(afv) : "v"(af));
            if (tid == 65 && pollBp)
                asm volatile("global_load_dword %0, %1, off sc0 sc1" : "=v"(bpv) : "v"(consA));

            // ---------- 8 inner steps ----------
            #pragma unroll
            for (int s = 0; s < CHUNK; ++s) {
                BPERM16(h);
                LGKM0();
                float acc0 = 0.f, acc1 = 0.f, acc2 = 0.f, acc3 = 0.f;
                FMAC_ALL();
                part2[s & 1][tid] = (acc0 + acc1) + (acc2 + acc3);
                LGKM0(); SBAR();
                const float* pb = &part2[s & 1][0];
                float p = pb[m] + pb[m + 256] + pb[m + 512] + pb[m + 768];
                h = tanh_fast(p + ap8[s] + bias_m);
                if (first) {
                    if (l < NLAY - 1)
                        st_coh_b32(Hout + (size_t)((k & 7) * CHUNK + s) * HID + m, h);
                    else if (k == NCHUNK - 1 && s == CHUNK - 1)
                        st_coh_b32(hfin + m, h);
                }
                if (s == 1) {
                    if (tid == 64 && pollIn) { WAIT_PIN(afv); pf_lds[0] = (afv >= (unsigned)(k + 2)); }
                    if (tid == 65 && pollBp) { WAIT_PIN(bpv); pf_lds[1] = (bpv >= (unsigned)(k - 6)); }
                }
                if (s == 2) {
                    havePF = false;
                    if (k + 1 < NCHUNK) {
                        const bool b1 = l0 || (pf_lds[0] != 0);
                        if (b1) {
                            havePF = true;
                            if (l0) {
                                #pragma unroll
                                for (int s2 = 0; s2 < CHUNK; ++s2)
                                    apn[s2] = Psrc[(size_t)(CHUNK * (k + 1) + s2) * HID + m];
                            } else {
                                const int nb = ((k + 1) & 7) * CHUNK;
                                #pragma unroll
                                for (int s2 = 0; s2 < CHUNK; ++s2)
                                    apn[s2] = ld_coh_b32(apbuf + (size_t)(nb + s2) * HID + m);
                            }
                        }
                    }
                }
            }
            // ---------- drain + publish ----------
            if (first) VMW0();
            SBAR();
            if (tid == 0) st_coh_u32(myHfl, (unsigned)(k + 1));
        }
    } else {
        // ===================== A role (l = 1..15) =====================
        float w[64];
        {
            const f4* wrow = (const f4*)(Wih + ((size_t)(l - 1) * HID + j) * HID + (c4 << 6));
            #pragma unroll
            for (int i = 0; i < 16; ++i) {
                f4 v = wrow[i];
                w[4*i+0] = v.x; w[4*i+1] = v.y; w[4*i+2] = v.z; w[4*i+3] = v.w;
            }
        }
        #pragma unroll
        for (int i = 0; i < 64; ++i) asm volatile("" : "+v"(w[i]));

        const float*    Hin    = Hring + ((size_t)(c * NLAY + (l - 1)) * QS) * HID;
        const unsigned* inflag = Hflag + c * NLAY + (l - 1);
        float*          Aout   = Apart + ((size_t)(c * NLAY + l) * QS) * HID;
        unsigned*       myAfl  = Aflag + c * NLAY + l;
        const unsigned* consB  = Hflag + c * NLAY + l;

        float h8[CHUNK], h8n[CHUNK];
        bool havePF = false;

        for (int k = 0; k < NCHUNK; ++k) {
            // ---------- chunk top ----------
            int pf2ok = 1;
            if (k >= CHUNK) pf2ok = pf_lds[1];
            const bool needbar = !havePF || !pf2ok;
            if (needbar) {
                if (tid == 0) {
                    if (!havePF) spin_ge(inflag, (unsigned)(k + 1), &dead);
                    if (!pf2ok)  spin_ge(consB, (unsigned)(k - 7), &dead);
                }
                SBAR();
            }
            if (havePF) {
                VMW0();
                #pragma unroll
                for (int s = 0; s < CHUNK; ++s) h8[s] = h8n[s];
            } else {
                const float* hbase = Hin + (size_t)(k & 7) * CHUNK * HID + m;
                #pragma unroll
                for (int s = 0; s < CHUNK; ++s)
                    h8[s] = ld_coh_b32(hbase + (size_t)s * HID);
                VMW0();
            }
            unsigned inv = 0u, bpv = 0u;
            const bool pollIn = (k + 1 < NCHUNK);
            const bool pollBp = (k + 1 >= CHUNK) && (k + 1 < NCHUNK);
            if (tid == 64 && pollIn)
                asm volatile("global_load_dword %0, %1, off sc0 sc1" : "=v"(inv) : "v"(inflag));
            if (tid == 65 && pollBp)
                asm volatile("global_load_dword %0, %1, off sc0 sc1" : "=v"(bpv) : "v"(consB));

            // ---------- 8 inner steps ----------
            #pragma unroll
            for (int s = 0; s < CHUNK; ++s) {
                BPERM16(h8[s]);
                LGKM0();
                float acc0 = 0.f, acc1 = 0.f, acc2 = 0.f, acc3 = 0.f;
                FMAC_ALL();
                part2[s & 1][tid] = (acc0 + acc1) + (acc2 + acc3);
                LGKM0(); SBAR();
                if (first) {
                    const float* pb = &part2[s & 1][0];
                    float p = pb[m] + pb[m + 256] + pb[m + 512] + pb[m + 768];
                    st_coh_b32(Aout + (size_t)((k & 7) * CHUNK + s) * HID + m, p);
                }
                if (s == 1) {
                    if (tid == 64 && pollIn) { WAIT_PIN(inv); pf_lds[0] = (inv >= (unsigned)(k + 2)); }
                    if (tid == 65 && pollBp) { WAIT_PIN(bpv); pf_lds[1] = (bpv >= (unsigned)(k - 6)); }
                }
                if (s == 2) {
                    havePF = false;
                    if (k + 1 < NCHUNK && pf_lds[0] != 0) {
                        havePF = true;
                        const float* nb = Hin + (size_t)((k + 1) & 7) * CHUNK * HID + m;
                        #pragma unroll
                        for (int s2 = 0; s2 < CHUNK; ++s2)
                            h8n[s2] = ld_coh_b32(nb + (size_t)s2 * HID);
                    }
                }
            }
            // ---------- drain + publish ----------
            if (first) VMW0();
            SBAR();
            if (tid == 0) st_coh_u32(myAfl, (unsigned)(k + 1));
        }
    }
}

// ---------------------------------------------------------------------------
// Kernel 3: out = fc_W @ concat(h0..h3) + fc_b
__global__ __launch_bounds__(1024) void fc_kernel(
    const float* __restrict__ hfinal, const float* __restrict__ fcW,
    const float* __restrict__ fcb, float* __restrict__ out)
{
    __shared__ float red[1024];
    const int tid = threadIdx.x;
    float v  = hfinal[tid];
    float p0 = fcW[tid] * v;
    float p1 = fcW[1024 + tid] * v;

    red[tid] = p0; __syncthreads();
    for (int st = 512; st > 0; st >>= 1) { if (tid < st) red[tid] += red[tid + st]; __syncthreads(); }
    if (tid == 0) out[0] = red[0] + fcb[0];
    __syncthreads();
    red[tid] = p1; __syncthreads();
    for (int st = 512; st > 0; st >>= 1) { if (tid < st) red[tid] += red[tid + st]; __syncthreads(); }
    if (tid == 0) out[1] = red[0] + fcb[1];
}

// ---------------------------------------------------------------------------
extern "C" void kernel_launch(void* const* d_in, const int* in_sizes, int n_in,
                              void* d_out, int out_size, void* d_ws, size_t ws_size,
                              hipStream_t stream)
{
    (void)in_sizes; (void)n_in; (void)out_size; (void)ws_size;
    const float* x        = (const float*)d_in[0];
    const float* lp_Wih0  = (const float*)d_in[1];
    const float* lp_Wih   = (const float*)d_in[2];
    const float* lp_Whh   = (const float*)d_in[3];
    const float* lp_bih   = (const float*)d_in[4];
    const float* lp_bhh   = (const float*)d_in[5];
    const float* lpv_Wih0 = (const float*)d_in[6];
    const float* lpv_Wih  = (const float*)d_in[7];
    const float* lpv_Whh  = (const float*)d_in[8];
    const float* lpv_bih  = (const float*)d_in[9];
    const float* lpv_bhh  = (const float*)d_in[10];
    const float* fcW      = (const float*)d_in[11];
    const float* fcb      = (const float*)d_in[12];

    float* ws      = (float*)d_ws;
    float* Pbuf    = ws + P_OFF;
    float* Hring   = ws + H_OFF;
    float* Apart   = ws + AP_OFF;
    float* hfinal  = ws + HF_OFF;
    unsigned* flags = (unsigned*)(ws + FLAG_OFF_FLOATS);

    hipMemsetAsync(flags, 0, NFLAGS * sizeof(unsigned), stream);

    proj_kernel<<<SEQL / TPB, 1024, 0, stream>>>(x, lp_Wih0, lpv_Wih0, Pbuf);

    rnn_pipe<<<124, 1024, 0, stream>>>(lp_Wih, lp_Whh, lp_bih, lp_bhh,
                                       lpv_Wih, lpv_Whh, lpv_bih, lpv_bhh,
                                       Pbuf, Hring, Apart, hfinal,
                                       flags, flags + 64);

    fc_kernel<<<1, 1024, 0, stream>>>(hfinal, fcW, fcb, (float*)d_out);
}

// Round 15
// 4818.703 us; speedup vs baseline: 1.0508x; 1.0508x over previous
//
#include <hip/hip_runtime.h>
#include <hip/hip_bf16.h>
#include <math.h>

#define SEQL   4096
#define NITEMS 512
#define HID    256
#define NLAY   16
#define QS     64      // ring slots = 8 chunks x 8 steps
#define CHUNK  8
#define NCHUNK (SEQL / CHUNK)
#define TPB    4

typedef float f4 __attribute__((ext_vector_type(4)));

// Workspace layout (float offsets)
#define P_OFF   ((size_t)0)                               // P[4][SEQL][HID]
#define H_OFF   (P_OFF + (size_t)4*SEQL*HID)              // Hring[4][NLAY][QS][HID]
#define AP_OFF  (H_OFF + (size_t)4*NLAY*QS*HID)           // Apart[4][NLAY][QS][HID]
#define HF_OFF  (AP_OFF + (size_t)4*NLAY*QS*HID)          // hfinal[4][HID]
#define FLAG_OFF_FLOATS (HF_OFF + (size_t)1024)
#define NFLAGS 256

// ---------------------------------------------------------------------------
__device__ __forceinline__ float ld_coh_b32(const float* p) {
    float r;
    asm volatile("global_load_dword %0, %1, off sc0 sc1" : "=v"(r) : "v"(p));
    return r;
}
__device__ __forceinline__ void st_coh_b32(float* p, float v) {
    asm volatile("global_store_dword %0, %1, off sc0 sc1" :: "v"(p), "v"(v) : "memory");
}
__device__ __forceinline__ void st_coh_u32(unsigned* p, unsigned v) {
    asm volatile("global_store_dword %0, %1, off sc0 sc1" :: "v"(p), "v"(v) : "memory");
}
__device__ __forceinline__ unsigned uload(const unsigned* p) {
    return __hip_atomic_load(p, __ATOMIC_RELAXED, __HIP_MEMORY_SCOPE_AGENT);
}

#define SBAR()  { __builtin_amdgcn_s_barrier(); __builtin_amdgcn_sched_barrier(0); }
#define LGKM0() { asm volatile("s_waitcnt lgkmcnt(0)" ::: "memory"); __builtin_amdgcn_sched_barrier(0); }
#define VMW0()  { asm volatile("s_waitcnt vmcnt(0)" ::: "memory"); __builtin_amdgcn_sched_barrier(0); }
// Wait own-wave vmem AND pin reg as output so uses can't hoist above (rule 18).
#define WAIT_PIN(reg) { asm volatile("s_waitcnt vmcnt(0)" : "+v"(reg) :: "memory"); \
                        __builtin_amdgcn_sched_barrier(0); }

__device__ __forceinline__ void spin_ge(const unsigned* p, unsigned target, bool* dead) {
    if (*dead) return;
    unsigned it = 0;
    while (uload(p) < target) {
        __builtin_amdgcn_s_sleep(1);
        if (++it > (1u << 20)) { *dead = true; break; }
    }
}

__device__ __forceinline__ float tanh_fast(float x) {
    return 1.f - __fdividef(2.f, __expf(2.f * x) + 1.f);
}

// Matvec core: readlane broadcast + plain full-rate v_fmac (R13/R15 A/B arm 2:
// DPP row_ror FMA appears to issue at ~6cyc; readlane+fmac pair ~2cyc each).
// Each lane's h register holds h[(c4<<6)|lane]; readlane(h,kk) broadcasts
// element kk of the wave's 64-wide k-chunk. Plain contiguous weights.
__device__ __forceinline__ void fma_rl(float h, const float (&w)[64],
                                       float* part, int tid) {
    float a0 = 0.f, a1 = 0.f;
    #pragma unroll
    for (int kk = 0; kk < 64; kk += 2) {
        float b0 = __int_as_float(__builtin_amdgcn_readlane(__float_as_int(h), kk));
        float b1 = __int_as_float(__builtin_amdgcn_readlane(__float_as_int(h), kk + 1));
        a0 = fmaf(b0, w[kk],     a0);
        a1 = fmaf(b1, w[kk + 1], a1);
    }
    part[tid] = a0 + a1;
}

// ---------------------------------------------------------------------------
// Kernel 1: input projection P[c][t][j] = sum_k Wih0_c[j,k] * x[t,k,c]
__global__ __launch_bounds__(1024) void proj_kernel(
    const float* __restrict__ x, const float* __restrict__ Wlp,
    const float* __restrict__ Wlpv, float* __restrict__ P)
{
    __shared__ float xs[TPB][4][NITEMS];
    const int tid = threadIdx.x;
    const int t0 = blockIdx.x * TPB;

    #pragma unroll
    for (int tt = 0; tt < TPB; ++tt) {
        const float2* src = (const float2*)(x + (size_t)(t0 + tt) * NITEMS * 4);
        float2 v = src[tid];
        int e = 2 * tid;
        xs[tt][e & 3][e >> 2]       = v.x;
        xs[tt][(e + 1) & 3][e >> 2] = v.y;
    }
    __syncthreads();

    const int c = tid >> 8, j = tid & 255;
    const float* W = (c == 1) ? Wlpv : Wlp;
    const float4* row = (const float4*)(W + (size_t)j * NITEMS);
    float acc[TPB] = {0.f, 0.f, 0.f, 0.f};
    #pragma unroll 4
    for (int k4 = 0; k4 < NITEMS / 4; ++k4) {
        float4 w = row[k4];
        #pragma unroll
        for (int tt = 0; tt < TPB; ++tt) {
            float4 xv = *(const float4*)(&xs[tt][c][k4 * 4]);
            acc[tt] = fmaf(w.x, xv.x, fmaf(w.y, xv.y, fmaf(w.z, xv.z, fmaf(w.w, xv.w, acc[tt]))));
        }
    }
    #pragma unroll
    for (int tt = 0; tt < TPB; ++tt)
        P[((size_t)c * SEQL + (t0 + tt)) * HID + j] = acc[tt];
}

// ---------------------------------------------------------------------------
// Kernel 2: layer-pipelined RNN. R12 chunked protocol (proven): early-poll +
// next-chunk prefetch, end-of-chunk full drain + publish. Readlane core.
// 124 blocks = 4 chains x (16 B + 15 A).
__global__ __launch_bounds__(1024) void rnn_pipe(
    const float* __restrict__ lp_Wih,  const float* __restrict__ lp_Whh,
    const float* __restrict__ lp_bih,  const float* __restrict__ lp_bhh,
    const float* __restrict__ lpv_Wih, const float* __restrict__ lpv_Whh,
    const float* __restrict__ lpv_bih, const float* __restrict__ lpv_bhh,
    const float* __restrict__ P, float* __restrict__ Hring,
    float* __restrict__ Apart, float* __restrict__ hfinal,
    unsigned* __restrict__ Hflag, unsigned* __restrict__ Aflag)
{
    __shared__ __align__(16) float part2[2][1024];
    __shared__ int pf_lds[2];   // [0]=next-chunk data ready, [1]=next-chunk bp ok

    const int b = blockIdx.x;
    if (b >= 124) return;
    const int tid = threadIdx.x;

    const int c = b / 31;
    const int r = b % 31;
    const int role = (r < NLAY) ? 0 : 1;
    const int l = (r < NLAY) ? r : (r - NLAY + 1);

    const float* Wih = (c == 1) ? lpv_Wih : lp_Wih;
    const float* Whh = (c == 1) ? lpv_Whh : lp_Whh;
    const float* bih = (c == 1) ? lpv_bih : lp_bih;
    const float* bhh = (c == 1) ? lpv_bhh : lp_bhh;

    const int j    = tid & 255;
    const int c4   = tid >> 8;
    const int lane = tid & 63;
    const int m    = (c4 << 6) | lane;
    const bool first = ((tid & 192) == 0);
    bool dead = false;

    if (role == 0) {
        // ===================== B role =====================
        const bool l0 = (l == 0);

        float w[64];
        {
            const f4* wrow = (const f4*)(Whh + ((size_t)l * HID + j) * HID + (c4 << 6));
            #pragma unroll
            for (int i = 0; i < 16; ++i) {
                f4 v = wrow[i];
                w[4*i+0] = v.x; w[4*i+1] = v.y; w[4*i+2] = v.z; w[4*i+3] = v.w;
            }
        }
        #pragma unroll
        for (int i = 0; i < 64; ++i) asm volatile("" : "+v"(w[i]));

        const float bias_m = bih[l * HID + m] + bhh[l * HID + m];

        const float*    Psrc  = P + (size_t)c * SEQL * HID;
        const float*    apbuf = Apart + ((size_t)(c * NLAY + l) * QS) * HID;
        const unsigned* af    = Aflag + c * NLAY + l;
        unsigned*       myHfl = Hflag + c * NLAY + l;
        const unsigned* consA = Aflag + c * NLAY + l + 1;   // valid when l<15
        float*          Hout  = Hring + ((size_t)(c * NLAY + l) * QS) * HID;
        float*          hfin  = hfinal + (size_t)c * HID;

        float h = 0.f;
        float ap8[CHUNK], apn[CHUNK];
        bool havePF = false;

        for (int k = 0; k < NCHUNK; ++k) {
            // ---------- chunk top ----------
            int pf2ok = 1;
            if (k >= CHUNK && l < NLAY - 1) pf2ok = pf_lds[1];
            const bool needbar = (!havePF && !l0) || !pf2ok;
            if (needbar) {
                if (tid == 0) {
                    if (!havePF && !l0) spin_ge(af, (unsigned)(k + 1), &dead);
                    if (!pf2ok) spin_ge(consA, (unsigned)(k - 7), &dead);
                }
                SBAR();
            }
            if (havePF) {
                VMW0();
                #pragma unroll
                for (int s = 0; s < CHUNK; ++s) ap8[s] = apn[s] + bias_m;
            } else {
                if (l0) {
                    #pragma unroll
                    for (int s = 0; s < CHUNK; ++s)
                        ap8[s] = Psrc[(size_t)(CHUNK * k + s) * HID + m] + bias_m;
                } else {
                    const int sbase = (k & 7) * CHUNK;
                    #pragma unroll
                    for (int s = 0; s < CHUNK; ++s)
                        ap8[s] = ld_coh_b32(apbuf + (size_t)(sbase + s) * HID + m);
                    VMW0();
                    #pragma unroll
                    for (int s = 0; s < CHUNK; ++s) ap8[s] += bias_m;
                }
            }
            // issue next-chunk polls (non-blocking; checked at s==1)
            unsigned afv = 0u, bpv = 0u;
            const bool pollIn = (!l0) && (k + 1 < NCHUNK);
            const bool pollBp = (l < NLAY - 1) && (k + 1 >= CHUNK) && (k + 1 < NCHUNK);
            if (tid == 64 && pollIn)
                asm volatile("global_load_dword %0, %1, off sc0 sc1" : "=v"(afv) : "v"(af));
            if (tid == 65 && pollBp)
                asm volatile("global_load_dword %0, %1, off sc0 sc1" : "=v"(bpv) : "v"(consA));

            // ---------- 8 inner steps ----------
            #pragma unroll
            for (int s = 0; s < CHUNK; ++s) {
                fma_rl(h, w, &part2[s & 1][0], tid);
                LGKM0(); SBAR();
                const float* pb = &part2[s & 1][0];
                float p = pb[m] + pb[m + 256] + pb[m + 512] + pb[m + 768];
                h = tanh_fast(p + ap8[s]);
                if (first) {
                    if (l < NLAY - 1)
                        st_coh_b32(Hout + (size_t)((k & 7) * CHUNK + s) * HID + m, h);
                    else if (k == NCHUNK - 1 && s == CHUNK - 1)
                        st_coh_b32(hfin + m, h);
                }
                if (s == 1) {
                    if (tid == 64 && pollIn) { WAIT_PIN(afv); pf_lds[0] = (afv >= (unsigned)(k + 2)); }
                    if (tid == 65 && pollBp) { WAIT_PIN(bpv); pf_lds[1] = (bpv >= (unsigned)(k - 6)); }
                }
                if (s == 2) {
                    havePF = false;
                    if (k + 1 < NCHUNK) {
                        const bool b1 = l0 || (pf_lds[0] != 0);
                        if (b1) {
                            havePF = true;
                            if (l0) {
                                #pragma unroll
                                for (int s2 = 0; s2 < CHUNK; ++s2)
                                    apn[s2] = Psrc[(size_t)(CHUNK * (k + 1) + s2) * HID + m];
                            } else {
                                const int nb = ((k + 1) & 7) * CHUNK;
                                #pragma unroll
                                for (int s2 = 0; s2 < CHUNK; ++s2)
                                    apn[s2] = ld_coh_b32(apbuf + (size_t)(nb + s2) * HID + m);
                            }
                        }
                    }
                }
            }
            // ---------- drain + publish ----------
            if (first) VMW0();
            SBAR();
            if (tid == 0) st_coh_u32(myHfl, (unsigned)(k + 1));
        }
    } else {
        // ===================== A role (l = 1..15) =====================
        float w[64];
        {
            const f4* wrow = (const f4*)(Wih + ((size_t)(l - 1) * HID + j) * HID + (c4 << 6));
            #pragma unroll
            for (int i = 0; i < 16; ++i) {
                f4 v = wrow[i];
                w[4*i+0] = v.x; w[4*i+1] = v.y; w[4*i+2] = v.z; w[4*i+3] = v.w;
            }
        }
        #pragma unroll
        for (int i = 0; i < 64; ++i) asm volatile("" : "+v"(w[i]));

        const float*    Hin    = Hring + ((size_t)(c * NLAY + (l - 1)) * QS) * HID;
        const unsigned* inflag = Hflag + c * NLAY + (l - 1);
        float*          Aout   = Apart + ((size_t)(c * NLAY + l) * QS) * HID;
        unsigned*       myAfl  = Aflag + c * NLAY + l;
        const unsigned* consB  = Hflag + c * NLAY + l;

        float h8[CHUNK], h8n[CHUNK];
        bool havePF = false;

        for (int k = 0; k < NCHUNK; ++k) {
            // ---------- chunk top ----------
            int pf2ok = 1;
            if (k >= CHUNK) pf2ok = pf_lds[1];
            const bool needbar = !havePF || !pf2ok;
            if (needbar) {
                if (tid == 0) {
                    if (!havePF) spin_ge(inflag, (unsigned)(k + 1), &dead);
                    if (!pf2ok)  spin_ge(consB, (unsigned)(k - 7), &dead);
                }
                SBAR();
            }
            if (havePF) {
                VMW0();
                #pragma unroll
                for (int s = 0; s < CHUNK; ++s) h8[s] = h8n[s];
            } else {
                const float* hbase = Hin + (size_t)(k & 7) * CHUNK * HID + m;
                #pragma unroll
                for (int s = 0; s < CHUNK; ++s)
                    h8[s] = ld_coh_b32(hbase + (size_t)s * HID);
                VMW0();
            }
            unsigned inv = 0u, bpv = 0u;
            const bool pollIn = (k + 1 < NCHUNK);
            const bool pollBp = (k + 1 >= CHUNK) && (k + 1 < NCHUNK);
            if (tid == 64 && pollIn)
                asm volatile("global_load_dword %0, %1, off sc0 sc1" : "=v"(inv) : "v"(inflag));
            if (tid == 65 && pollBp)
                asm volatile("global_load_dword %0, %1, off sc0 sc1" : "=v"(bpv) : "v"(consB));

            // ---------- 8 inner steps ----------
            #pragma unroll
            for (int s = 0; s < CHUNK; ++s) {
                fma_rl(h8[s], w, &part2[s & 1][0], tid);
                LGKM0(); SBAR();
                if (first) {
                    const float* pb = &part2[s & 1][0];
                    float p = pb[m] + pb[m + 256] + pb[m + 512] + pb[m + 768];
                    st_coh_b32(Aout + (size_t)((k & 7) * CHUNK + s) * HID + m, p);
                }
                if (s == 1) {
                    if (tid == 64 && pollIn) { WAIT_PIN(inv); pf_lds[0] = (inv >= (unsigned)(k + 2)); }
                    if (tid == 65 && pollBp) { WAIT_PIN(bpv); pf_lds[1] = (bpv >= (unsigned)(k - 6)); }
                }
                if (s == 2) {
                    havePF = false;
                    if (k + 1 < NCHUNK && pf_lds[0] != 0) {
                        havePF = true;
                        const float* nb = Hin + (size_t)((k + 1) & 7) * CHUNK * HID + m;
                        #pragma unroll
                        for (int s2 = 0; s2 < CHUNK; ++s2)
                            h8n[s2] = ld_coh_b32(nb + (size_t)s2 * HID);
                    }
                }
            }
            // ---------- drain + publish ----------
            if (first) VMW0();
            SBAR();
            if (tid == 0) st_coh_u32(myAfl, (unsigned)(k + 1));
        }
    }
}

// ---------------------------------------------------------------------------
// Kernel 3: out = fc_W @ concat(h0..h3) + fc_b
__global__ __launch_bounds__(1024) void fc_kernel(
    const float* __restrict__ hfinal, const float* __restrict__ fcW,
    const float* __restrict__ fcb, float* __restrict__ out)
{
    __shared__ float red[1024];
    const int tid = threadIdx.x;
    float v  = hfinal[tid];
    float p0 = fcW[tid] * v;
    float p1 = fcW[1024 + tid] * v;

    red[tid] = p0; __syncthreads();
    for (int st = 512; st > 0; st >>= 1) { if (tid < st) red[tid] += red[tid + st]; __syncthreads(); }
    if (tid == 0) out[0] = red[0] + fcb[0];
    __syncthreads();
    red[tid] = p1; __syncthreads();
    for (int st = 512; st > 0; st >>= 1) { if (tid < st) red[tid] += red[tid + st]; __syncthreads(); }
    if (tid == 0) out[1] = red[0] + fcb[1];
}

// ---------------------------------------------------------------------------
extern "C" void kernel_launch(void* const* d_in, const int* in_sizes, int n_in,
                              void* d_out, int out_size, void* d_ws, size_t ws_size,
                              hipStream_t stream)
{
    (void)in_sizes; (void)n_in; (void)out_size; (void)ws_size;
    const float* x        = (const float*)d_in[0];
    const float* lp_Wih0  = (const float*)d_in[1];
    const float* lp_Wih   = (const float*)d_in[2];
    const float* lp_Whh   = (const float*)d_in[3];
    const float* lp_bih   = (const float*)d_in[4];
    const float* lp_bhh   = (const float*)d_in[5];
    const float* lpv_Wih0 = (const float*)d_in[6];
    const float* lpv_Wih  = (const float*)d_in[7];
    const float* lpv_Whh  = (const float*)d_in[8];
    const float* lpv_bih  = (const float*)d_in[9];
    const float* lpv_bhh  = (const float*)d_in[10];
    const float* fcW      = (const float*)d_in[11];
    const float* fcb      = (const float*)d_in[12];

    float* ws      = (float*)d_ws;
    float* Pbuf    = ws + P_OFF;
    float* Hring   = ws + H_OFF;
    float* Apart   = ws + AP_OFF;
    float* hfinal  = ws + HF_OFF;
    unsigned* flags = (unsigned*)(ws + FLAG_OFF_FLOATS);

    hipMemsetAsync(flags, 0, NFLAGS * sizeof(unsigned), stream);

    proj_kernel<<<SEQL / TPB, 1024, 0, stream>>>(x, lp_Wih0, lpv_Wih0, Pbuf);

    rnn_pipe<<<124, 1024, 0, stream>>>(lp_Wih, lp_Whh, lp_bih, lp_bhh,
                                       lpv_Wih, lpv_Whh, lpv_bih, lpv_bhh,
                                       Pbuf, Hring, Apart, hfinal,
                                       flags, flags + 64);

    fc_kernel<<<1, 1024, 0, stream>>>(hfinal, fcW, fcb, (float*)d_out);
}